// Round 8
// baseline (597.932 us; speedup 1.0000x reference)
//
#include <hip/hip_runtime.h>

#define F_DIM 128
#define NG 3
#define XCDS 8
#define NSTRIPE 4   // 4 stripes x 32 bf16 = 64B line per (node,stripe)
#define EPT 8       // edges per thread in partitioned kernels

typedef __attribute__((ext_vector_type(8))) short short8_t;
typedef __attribute__((ext_vector_type(4))) float f32x4;
typedef __attribute__((ext_vector_type(2))) float f32x2;

__device__ __forceinline__ unsigned short f2bf(float f) {
    unsigned int x = __float_as_uint(f);
    unsigned int r = x + 0x7fffu + ((x >> 16) & 1u);  // RNE
    return (unsigned short)(r >> 16);
}
__device__ __forceinline__ float bflo(unsigned int u) { return __uint_as_float(u << 16); }
__device__ __forceinline__ float bfhi(unsigned int u) { return __uint_as_float(u & 0xffff0000u); }

struct GArgs {
    const int* src[NG]; const int* dst[NG];
    const float* X[NG]; const float* W[NG]; const float* b[NG];
    float* out[NG];
    unsigned short* Xps[NG];  // bf16, stripe-major [4][N][32]
    int* counts[NG]; int* offsets[NG]; int* cursor[NG];
    float* dinv[NG]; int* sorted[NG];
    int* totals;  // [NG]
};

// ---- histogram, XCD-partitioned by dst-range ---------------------------------
__global__ __launch_bounds__(256) void hist_kernel(GArgs a, int g0, int E, int nPerX) {
    int g = g0 + blockIdx.y;
    int xcd = blockIdx.x % XCDS;
    int lo = xcd * nPerX, hi = lo + nPerX;
    const int* dst = a.dst[g];
    int* counts = a.counts[g];
    int base = (blockIdx.x / XCDS) * (256 * EPT) + threadIdx.x;
#pragma unroll
    for (int i = 0; i < EPT; ++i) {
        int e = base + i * 256;
        if (e < E) {
            int d = dst[e];
            if (d >= lo && d < hi) atomicAdd(&counts[d], 1);
        }
    }
}

// ---- offsets via wave-scan + one atomic per wave (order-free buckets) --------
__global__ __launch_bounds__(256) void offs_kernel(GArgs a, int g0, int n) {
    int g = g0 + blockIdx.y;
    int i = blockIdx.x * 256 + threadIdx.x;
    int lane = threadIdx.x & 63;
    int c = (i < n) ? a.counts[g][i] : 0;
    int v = c;
#pragma unroll
    for (int off = 1; off < 64; off <<= 1) {
        int u = __shfl_up(v, off, 64);
        if (lane >= off) v += u;
    }
    int wsum = __shfl(v, 63, 64);
    int base = 0;
    if (lane == 63) base = atomicAdd(&a.totals[g], wsum);
    base = __shfl(base, 63, 64);
    int off0 = base + v - c;
    if (i < n) {
        a.offsets[g][i] = off0;
        a.cursor[g][i] = off0;
        a.dinv[g][i] = rsqrtf((float)c + 1.0f);
    }
}

// ---- bucket-scatter, XCD-partitioned by dst-range ----------------------------
__global__ __launch_bounds__(256) void build_kernel(GArgs a, int g0, int E, int nPerX) {
    int g = g0 + blockIdx.y;
    int xcd = blockIdx.x % XCDS;
    int lo = xcd * nPerX, hi = lo + nPerX;
    const int* dst = a.dst[g];
    const int* src = a.src[g];
    int* cursor = a.cursor[g];
    int* sorted = a.sorted[g];
    int base = (blockIdx.x / XCDS) * (256 * EPT) + threadIdx.x;
#pragma unroll
    for (int i = 0; i < EPT; ++i) {
        int e = base + i * 256;
        if (e < E) {
            int d = dst[e];
            if (d >= lo && d < hi) {
                int p = atomicAdd(&cursor[d], 1);
                sorted[p] = src[e];
            }
        }
    }
}

// ---- MFMA bf16 GEMM: Xps(bf16, stripe-major [4][N][32]) = dinv*(X@W + b) -----
__global__ __launch_bounds__(256) void gemm_kernel(GArgs a, int g0, int n) {
    int g = g0 + blockIdx.y;
    __shared__ unsigned short Xl[128 * 128];
    __shared__ unsigned short Wt[128 * 128];
    const int t = threadIdx.x;
    const int row0 = blockIdx.x * 128;
    const float* X = a.X[g];
    const float* W = a.W[g];
    char* XlB = (char*)Xl;
    char* WtB = (char*)Wt;

    for (int i = t; i < 128 * 16; i += 256) {
        int r = i >> 4, kc = i & 15;
        int row = row0 + r;
        float4 x0 = make_float4(0.f, 0.f, 0.f, 0.f), x1 = x0;
        if (row < n) {
            const float4* xp = (const float4*)(X + (size_t)row * F_DIM + kc * 8);
            x0 = xp[0]; x1 = xp[1];
        }
        uint4 pk;
        pk.x = (unsigned)f2bf(x0.x) | ((unsigned)f2bf(x0.y) << 16);
        pk.y = (unsigned)f2bf(x0.z) | ((unsigned)f2bf(x0.w) << 16);
        pk.z = (unsigned)f2bf(x1.x) | ((unsigned)f2bf(x1.y) << 16);
        pk.w = (unsigned)f2bf(x1.z) | ((unsigned)f2bf(x1.w) << 16);
        unsigned int ad = (unsigned)((r << 8) + (kc << 4)) ^ (unsigned)((r & 15) << 4);
        *(uint4*)(XlB + ad) = pk;
    }
    for (int i = t; i < 128 * 16; i += 256) {
        int nn = i & 127, kc = i >> 7;
        const float* wp = W + (size_t)(kc * 8) * F_DIM + nn;
        uint4 pk;
        pk.x = (unsigned)f2bf(wp[0])   | ((unsigned)f2bf(wp[128]) << 16);
        pk.y = (unsigned)f2bf(wp[256]) | ((unsigned)f2bf(wp[384]) << 16);
        pk.z = (unsigned)f2bf(wp[512]) | ((unsigned)f2bf(wp[640]) << 16);
        pk.w = (unsigned)f2bf(wp[768]) | ((unsigned)f2bf(wp[896]) << 16);
        unsigned int ad = (unsigned)((nn << 8) + (kc << 4)) ^ (unsigned)((nn & 15) << 4);
        *(uint4*)(WtB + ad) = pk;
    }
    __syncthreads();

    const int l = t & 63;
    const int wv = t >> 6;
    const int wr = wv >> 1, wc = wv & 1;
    const int lm = l & 15;
    const int lk = l >> 4;

    f32x4 acc[4][4] = {};
#pragma unroll
    for (int ks = 0; ks < 4; ++ks) {
        const int kb = ks * 64 + lk * 16;
        short8_t af[4], bv[4];
#pragma unroll
        for (int mt = 0; mt < 4; ++mt) {
            int r = wr * 64 + mt * 16 + lm;
            unsigned int ad = (unsigned)((r << 8) + kb) ^ (unsigned)((r & 15) << 4);
            af[mt] = *(const short8_t*)(XlB + ad);
        }
#pragma unroll
        for (int nt = 0; nt < 4; ++nt) {
            int c = wc * 64 + nt * 16 + lm;
            unsigned int ad = (unsigned)((c << 8) + kb) ^ (unsigned)((c & 15) << 4);
            bv[nt] = *(const short8_t*)(WtB + ad);
        }
#pragma unroll
        for (int mt = 0; mt < 4; ++mt)
#pragma unroll
            for (int nt = 0; nt < 4; ++nt)
                acc[mt][nt] = __builtin_amdgcn_mfma_f32_16x16x32_bf16(af[mt], bv[nt],
                                                                      acc[mt][nt], 0, 0, 0);
    }

    const float* bia = a.b[g];
    const float* dinv = a.dinv[g];
    unsigned short* Xps = a.Xps[g];
#pragma unroll
    for (int nt = 0; nt < 4; ++nt) {
        int col = wc * 64 + nt * 16 + lm;
        float bc = bia[col];
        int stripe = col >> 5, c32 = col & 31;  // stripe 0..3
#pragma unroll
        for (int mt = 0; mt < 4; ++mt) {
            int rbase = row0 + wr * 64 + mt * 16 + lk * 4;
#pragma unroll
            for (int r = 0; r < 4; ++r) {
                int row = rbase + r;
                if (row < n) {
                    float v = (acc[mt][nt][r] + bc) * dinv[row];
                    Xps[((size_t)stripe * n + row) * 32 + c32] = f2bf(v);
                }
            }
        }
    }
}

// ---- aggregation, stripe-partitioned: blockIdx%4 = stripe (-> XCD affinity) --
// wave handles one (node, stripe): 16 lanes per src 64B line, 4 srcs in
// flight; cross-subgroup reduce via shfl_xor(16,32); NT loads/stores for
// streaming data so the 3.2MB stripe slice stays L2-resident.
__global__ __launch_bounds__(256) void agg_kernel(GArgs a, int g, int n) {
    const int stripe = blockIdx.x & (NSTRIPE - 1);
    const int node = (blockIdx.x >> 2) * 4 + (threadIdx.x >> 6);
    if (node >= n) return;
    const int l = threadIdx.x & 63;
    const int c = l & 15;       // u32 column within stripe (2 features)
    const int kk = l >> 4;      // sub-group 0..3
    const unsigned int* Xp = (const unsigned int*)a.Xps[g] + (size_t)stripe * n * 16;
    const int* sorted = a.sorted[g];
    int beg = a.offsets[g][node];
    int cnt = a.counts[g][node];
    float ax = 0.f, ay = 0.f;
    for (int j = 0; j < cnt; j += 64) {
        int m = min(cnt - j, 64);
        int s = (l < m) ? __builtin_nontemporal_load(&sorted[beg + j + l]) : 0;
        for (int k = 0; k < m; k += 4) {
            int kks = k + kk;
            int sk = __shfl(s, kks & 63, 64);
            if (kks < m) {
                unsigned int u = Xp[(size_t)sk * 16 + c];
                ax += bflo(u);
                ay += bfhi(u);
            }
        }
    }
    ax += __shfl_xor(ax, 16, 64); ax += __shfl_xor(ax, 32, 64);
    ay += __shfl_xor(ay, 16, 64); ay += __shfl_xor(ay, 32, 64);
    unsigned int u0 = Xp[(size_t)node * 16 + c];   // self-loop term (stripe-local)
    ax += bflo(u0);
    ay += bfhi(u0);
    float dd = a.dinv[g][node];
    if (kk == 0) {
        f32x2* o = (f32x2*)((float*)a.out[g] + (size_t)node * F_DIM + stripe * 32 + c * 2);
        f32x2 val;
        val.x = ax * dd;
        val.y = ay * dd;
        __builtin_nontemporal_store(val, o);
    }
}

extern "C" void kernel_launch(void* const* d_in, const int* in_sizes, int n_in,
                              void* d_out, int out_size, void* d_ws, size_t ws_size,
                              hipStream_t stream) {
    const float* Xin[NG] = {(const float*)d_in[0], (const float*)d_in[1], (const float*)d_in[2]};
    const int* ei[NG] = {(const int*)d_in[3], (const int*)d_in[4], (const int*)d_in[5]};
    const float* Wk[NG] = {(const float*)d_in[6], (const float*)d_in[8], (const float*)d_in[10]};
    const float* bk[NG] = {(const float*)d_in[7], (const float*)d_in[9], (const float*)d_in[11]};

    const int N = in_sizes[0] / F_DIM;  // 50000
    const int E = in_sizes[3] / 2;      // 800000
    float* out = (float*)d_out;

    const size_t xps_b = (size_t)N * F_DIM * 2;  // bf16
    const size_t sorted_b = (size_t)E * 4;
    const size_t nb = (size_t)N * 4;
    const size_t per = ((xps_b + sorted_b + 5 * nb + 64 + 255) / 256) * 256;
    const bool fused = ws_size >= (size_t)NG * per;
    char* base = (char*)d_ws;

    GArgs a;
    for (int r = 0; r < NG; ++r) {
        char* s = base + (size_t)(fused ? r : 0) * per;
        a.Xps[r] = (unsigned short*)s;
        a.sorted[r] = (int*)(s + xps_b);
        a.counts[r] = (int*)(s + xps_b + sorted_b);
        a.offsets[r] = (int*)(s + xps_b + sorted_b + nb);
        a.cursor[r] = (int*)(s + xps_b + sorted_b + 2 * nb);
        a.dinv[r] = (float*)(s + xps_b + sorted_b + 3 * nb);
        a.src[r] = ei[r];
        a.dst[r] = ei[r] + E;
        a.X[r] = Xin[r];
        a.W[r] = Wk[r];
        a.b[r] = bk[r];
        a.out[r] = out + (size_t)r * N * F_DIM;
    }
    a.totals = (int*)(base + xps_b + sorted_b + 4 * nb);

    const dim3 blk(256);
    const int nPerX = (N + XCDS - 1) / XCDS;
    const int chunks = (E + 256 * EPT - 1) / (256 * EPT);
    const int gP = chunks * XCDS;
    const int gN = (N + 255) / 256;
    const int gR = (N + 127) / 128;
    const int gA = ((N + 3) / 4) * NSTRIPE;  // (node-quads) x 4 stripes

    if (fused) {
        for (int r = 0; r < NG; ++r) (void)hipMemsetAsync(a.counts[r], 0, nb, stream);
        (void)hipMemsetAsync(a.totals, 0, NG * sizeof(int), stream);
        hist_kernel<<<dim3(gP, NG), blk, 0, stream>>>(a, 0, E, nPerX);
        offs_kernel<<<dim3(gN, NG), blk, 0, stream>>>(a, 0, N);
        build_kernel<<<dim3(gP, NG), blk, 0, stream>>>(a, 0, E, nPerX);
        gemm_kernel<<<dim3(gR, NG), blk, 0, stream>>>(a, 0, N);
        for (int g = 0; g < NG; ++g)  // sequential: keep 3.2MB stripe slice per XCD-L2
            agg_kernel<<<dim3(gA, 1), blk, 0, stream>>>(a, g, N);
    } else {
        for (int g = 0; g < NG; ++g) {
            (void)hipMemsetAsync(a.counts[g], 0, nb, stream);
            (void)hipMemsetAsync(a.totals, 0, NG * sizeof(int), stream);
            hist_kernel<<<dim3(gP, 1), blk, 0, stream>>>(a, g, E, nPerX);
            offs_kernel<<<dim3(gN, 1), blk, 0, stream>>>(a, g, N);
            build_kernel<<<dim3(gP, 1), blk, 0, stream>>>(a, g, E, nPerX);
            gemm_kernel<<<dim3(gR, 1), blk, 0, stream>>>(a, g, N);
            agg_kernel<<<dim3(gA, 1), blk, 0, stream>>>(a, g, N);
        }
    }
}

// Round 9
// 335.073 us; speedup vs baseline: 1.7845x; 1.7845x over previous
//
#include <hip/hip_runtime.h>

#define F_DIM 128
#define NG 3
#define XCDS 8
#define EPT 8        // edges per thread in build
#define CAP 48       // fixed per-node CSR capacity (mean deg 16, max ~35)
#define SPILL_CAP 8192

typedef __attribute__((ext_vector_type(8))) short short8_t;
typedef __attribute__((ext_vector_type(4))) float f32x4;

__device__ __forceinline__ unsigned short f2bf(float f) {
    unsigned int x = __float_as_uint(f);
    unsigned int r = x + 0x7fffu + ((x >> 16) & 1u);  // RNE
    return (unsigned short)(r >> 16);
}
__device__ __forceinline__ float bflo(unsigned int u) { return __uint_as_float(u << 16); }
__device__ __forceinline__ float bfhi(unsigned int u) { return __uint_as_float(u & 0xffff0000u); }

struct GArgs {
    const int* src[NG]; const int* dst[NG];
    const float* X[NG]; const float* W[NG]; const float* b[NG];
    float* out[NG];
    unsigned short* Xps[NG];  // bf16 row-major [N][128], pre-scaled by dinv[row]
    int* cursor[NG];          // [N] bucket cursors (init i*CAP)
    int* cstore[NG];          // [N] stored counts (<=CAP)
    float* dinv[NG];          // [N]
    int* sorted[NG];          // [N*CAP]
    int* spill[NG];           // [SPILL_CAP*2] (src,dst) pairs
    int* spill_n[NG];         // [1]
};

// ---- init: cursor[i] = i*CAP; spill_n = 0 ------------------------------------
__global__ __launch_bounds__(256) void init_kernel(GArgs a, int g0, int n) {
    int g = g0 + blockIdx.y;
    int i = blockIdx.x * 256 + threadIdx.x;
    if (i < n) a.cursor[g][i] = i * CAP;
    if (i == 0) a.spill_n[g][0] = 0;
}

// ---- bucket-scatter, XCD-partitioned by dst-range. Also produces degrees. ----
__global__ __launch_bounds__(256) void build_kernel(GArgs a, int g0, int E, int nPerX) {
    int g = g0 + blockIdx.y;
    int xcd = blockIdx.x % XCDS;
    int lo = xcd * nPerX, hi = lo + nPerX;
    const int* dst = a.dst[g];
    const int* src = a.src[g];
    int* cursor = a.cursor[g];
    int* sorted = a.sorted[g];
    int base = (blockIdx.x / XCDS) * (256 * EPT) + threadIdx.x;
#pragma unroll
    for (int i = 0; i < EPT; ++i) {
        int e = base + i * 256;
        if (e < E) {
            int d = dst[e];
            if (d >= lo && d < hi) {
                int p = atomicAdd(&cursor[d], 1);
                if (p < d * CAP + CAP) {
                    sorted[p] = src[e];
                } else {
                    int sp = atomicAdd(a.spill_n[g], 1);
                    if (sp < SPILL_CAP) {
                        a.spill[g][2 * sp] = src[e];
                        a.spill[g][2 * sp + 1] = d;
                    }
                }
            }
        }
    }
}

// ---- counts + dinv from cursors ----------------------------------------------
__global__ __launch_bounds__(256) void counts_kernel(GArgs a, int g0, int n) {
    int g = g0 + blockIdx.y;
    int i = blockIdx.x * 256 + threadIdx.x;
    if (i >= n) return;
    int deg = a.cursor[g][i] - i * CAP;
    a.cstore[g][i] = min(deg, CAP);
    a.dinv[g][i] = rsqrtf((float)deg + 1.0f);
}

// ---- MFMA bf16 GEMM: Xps(bf16 row-major) = dinv[row] * (X @ W + b) -----------
__global__ __launch_bounds__(256) void gemm_kernel(GArgs a, int g0, int n) {
    int g = g0 + blockIdx.y;
    __shared__ unsigned short Xl[128 * 128];
    __shared__ unsigned short Wt[128 * 128];
    const int t = threadIdx.x;
    const int row0 = blockIdx.x * 128;
    const float* X = a.X[g];
    const float* W = a.W[g];
    char* XlB = (char*)Xl;
    char* WtB = (char*)Wt;

    for (int i = t; i < 128 * 16; i += 256) {
        int r = i >> 4, kc = i & 15;
        int row = row0 + r;
        float4 x0 = make_float4(0.f, 0.f, 0.f, 0.f), x1 = x0;
        if (row < n) {
            const float4* xp = (const float4*)(X + (size_t)row * F_DIM + kc * 8);
            x0 = xp[0]; x1 = xp[1];
        }
        uint4 pk;
        pk.x = (unsigned)f2bf(x0.x) | ((unsigned)f2bf(x0.y) << 16);
        pk.y = (unsigned)f2bf(x0.z) | ((unsigned)f2bf(x0.w) << 16);
        pk.z = (unsigned)f2bf(x1.x) | ((unsigned)f2bf(x1.y) << 16);
        pk.w = (unsigned)f2bf(x1.z) | ((unsigned)f2bf(x1.w) << 16);
        unsigned int ad = (unsigned)((r << 8) + (kc << 4)) ^ (unsigned)((r & 15) << 4);
        *(uint4*)(XlB + ad) = pk;
    }
    for (int i = t; i < 128 * 16; i += 256) {
        int nn = i & 127, kc = i >> 7;
        const float* wp = W + (size_t)(kc * 8) * F_DIM + nn;
        uint4 pk;
        pk.x = (unsigned)f2bf(wp[0])   | ((unsigned)f2bf(wp[128]) << 16);
        pk.y = (unsigned)f2bf(wp[256]) | ((unsigned)f2bf(wp[384]) << 16);
        pk.z = (unsigned)f2bf(wp[512]) | ((unsigned)f2bf(wp[640]) << 16);
        pk.w = (unsigned)f2bf(wp[768]) | ((unsigned)f2bf(wp[896]) << 16);
        unsigned int ad = (unsigned)((nn << 8) + (kc << 4)) ^ (unsigned)((nn & 15) << 4);
        *(uint4*)(WtB + ad) = pk;
    }
    __syncthreads();

    const int l = t & 63;
    const int wv = t >> 6;
    const int wr = wv >> 1, wc = wv & 1;
    const int lm = l & 15;
    const int lk = l >> 4;

    f32x4 acc[4][4] = {};
#pragma unroll
    for (int ks = 0; ks < 4; ++ks) {
        const int kb = ks * 64 + lk * 16;
        short8_t af[4], bv[4];
#pragma unroll
        for (int mt = 0; mt < 4; ++mt) {
            int r = wr * 64 + mt * 16 + lm;
            unsigned int ad = (unsigned)((r << 8) + kb) ^ (unsigned)((r & 15) << 4);
            af[mt] = *(const short8_t*)(XlB + ad);
        }
#pragma unroll
        for (int nt = 0; nt < 4; ++nt) {
            int c = wc * 64 + nt * 16 + lm;
            unsigned int ad = (unsigned)((c << 8) + kb) ^ (unsigned)((c & 15) << 4);
            bv[nt] = *(const short8_t*)(WtB + ad);
        }
#pragma unroll
        for (int mt = 0; mt < 4; ++mt)
#pragma unroll
            for (int nt = 0; nt < 4; ++nt)
                acc[mt][nt] = __builtin_amdgcn_mfma_f32_16x16x32_bf16(af[mt], bv[nt],
                                                                      acc[mt][nt], 0, 0, 0);
    }

    const float* bia = a.b[g];
    const float* dinv = a.dinv[g];
    unsigned short* Xps = a.Xps[g];
#pragma unroll
    for (int nt = 0; nt < 4; ++nt) {
        int col = wc * 64 + nt * 16 + lm;
        float bc = bia[col];
#pragma unroll
        for (int mt = 0; mt < 4; ++mt) {
            int rbase = row0 + wr * 64 + mt * 16 + lk * 4;
#pragma unroll
            for (int r = 0; r < 4; ++r) {
                int row = rbase + r;
                if (row < n) {
                    float v = (acc[mt][nt][r] + bc) * dinv[row];
                    Xps[(size_t)row * F_DIM + col] = f2bf(v);
                }
            }
        }
    }
}

// ---- aggregation (row-major, fused over graphs): one wave per node -----------
__global__ __launch_bounds__(256) void agg_kernel(GArgs a, int g0, int n) {
    int g = g0 + blockIdx.y;
    int wave = (blockIdx.x * 256 + threadIdx.x) >> 6;
    if (wave >= n) return;
    int lane = threadIdx.x & 63;
    const unsigned int* Xp = (const unsigned int*)a.Xps[g];  // 64 u32 per row
    const int* sorted = a.sorted[g];
    int beg = wave * CAP;
    int cnt = a.cstore[g][wave];
    unsigned int u0 = Xp[(size_t)wave * 64 + lane];
    float ax = bflo(u0), ay = bfhi(u0);
    for (int j = 0; j < cnt;) {
        int m = min(cnt - j, 64);
        int s = (j + lane < cnt) ? sorted[beg + j + lane] : 0;
        for (int k = 0; k < m; ++k) {
            int sk = __shfl(s, k, 64);
            unsigned int v = Xp[(size_t)sk * 64 + lane];
            ax += bflo(v);
            ay += bfhi(v);
        }
        j += m;
    }
    float dd = a.dinv[g][wave];
    ((float2*)a.out[g])[(size_t)wave * 64 + lane] = make_float2(ax * dd, ay * dd);
}

// ---- spill cleanup: out[d] += dinv[d] * Xps[s] for overflow edges ------------
__global__ __launch_bounds__(128) void spill_kernel(GArgs a, int g0) {
    int g = g0 + blockIdx.y;
    int ns = min(a.spill_n[g][0], SPILL_CAP);
    const unsigned short* Xps = a.Xps[g];
    const float* dinv = a.dinv[g];
    float* out = a.out[g];
    for (int i = blockIdx.x; i < ns; i += gridDim.x) {
        int s = a.spill[g][2 * i];
        int d = a.spill[g][2 * i + 1];
        float w = dinv[d];
        int f = threadIdx.x;
        float v = __uint_as_float(((unsigned int)Xps[(size_t)s * F_DIM + f]) << 16);
        unsafeAtomicAdd(&out[(size_t)d * F_DIM + f], w * v);
    }
}

extern "C" void kernel_launch(void* const* d_in, const int* in_sizes, int n_in,
                              void* d_out, int out_size, void* d_ws, size_t ws_size,
                              hipStream_t stream) {
    const float* Xin[NG] = {(const float*)d_in[0], (const float*)d_in[1], (const float*)d_in[2]};
    const int* ei[NG] = {(const int*)d_in[3], (const int*)d_in[4], (const int*)d_in[5]};
    const float* Wk[NG] = {(const float*)d_in[6], (const float*)d_in[8], (const float*)d_in[10]};
    const float* bk[NG] = {(const float*)d_in[7], (const float*)d_in[9], (const float*)d_in[11]};

    const int N = in_sizes[0] / F_DIM;  // 50000
    const int E = in_sizes[3] / 2;      // 800000
    float* out = (float*)d_out;

    const size_t xps_b = (size_t)N * F_DIM * 2;       // bf16
    const size_t sorted_b = (size_t)N * CAP * 4;
    const size_t nb = (size_t)N * 4;
    const size_t spill_b = (size_t)SPILL_CAP * 8 + 64;
    const size_t per = ((xps_b + sorted_b + 3 * nb + spill_b + 255) / 256) * 256;
    const bool fused = ws_size >= (size_t)NG * per;
    char* base = (char*)d_ws;

    GArgs a;
    for (int r = 0; r < NG; ++r) {
        char* s = base + (size_t)(fused ? r : 0) * per;
        a.Xps[r] = (unsigned short*)s;
        a.sorted[r] = (int*)(s + xps_b);
        a.cursor[r] = (int*)(s + xps_b + sorted_b);
        a.cstore[r] = (int*)(s + xps_b + sorted_b + nb);
        a.dinv[r] = (float*)(s + xps_b + sorted_b + 2 * nb);
        a.spill[r] = (int*)(s + xps_b + sorted_b + 3 * nb);
        a.spill_n[r] = (int*)(s + xps_b + sorted_b + 3 * nb + spill_b - 64);
        a.src[r] = ei[r];
        a.dst[r] = ei[r] + E;
        a.X[r] = Xin[r];
        a.W[r] = Wk[r];
        a.b[r] = bk[r];
        a.out[r] = out + (size_t)r * N * F_DIM;
    }

    const dim3 blk(256);
    const int nPerX = (N + XCDS - 1) / XCDS;
    const int chunks = (E + 256 * EPT - 1) / (256 * EPT);
    const int gP = chunks * XCDS;
    const int gN = (N + 255) / 256;
    const int gR = (N + 127) / 128;
    const int gA = (N * 64 + 255) / 256;

    if (fused) {
        init_kernel<<<dim3(gN, NG), blk, 0, stream>>>(a, 0, N);
        build_kernel<<<dim3(gP, NG), blk, 0, stream>>>(a, 0, E, nPerX);
        counts_kernel<<<dim3(gN, NG), blk, 0, stream>>>(a, 0, N);
        gemm_kernel<<<dim3(gR, NG), blk, 0, stream>>>(a, 0, N);
        agg_kernel<<<dim3(gA, NG), blk, 0, stream>>>(a, 0, N);
        spill_kernel<<<dim3(16, NG), dim3(128), 0, stream>>>(a, 0);
    } else {
        for (int g = 0; g < NG; ++g) {
            init_kernel<<<dim3(gN, 1), blk, 0, stream>>>(a, g, N);
            build_kernel<<<dim3(gP, 1), blk, 0, stream>>>(a, g, E, nPerX);
            counts_kernel<<<dim3(gN, 1), blk, 0, stream>>>(a, g, N);
            gemm_kernel<<<dim3(gR, 1), blk, 0, stream>>>(a, g, N);
            agg_kernel<<<dim3(gA, 1), blk, 0, stream>>>(a, g, N);
            spill_kernel<<<dim3(16, 1), dim3(128), 0, stream>>>(a, g);
        }
    }
}

// Round 10
// 266.762 us; speedup vs baseline: 2.2414x; 1.2561x over previous
//
#include <hip/hip_runtime.h>

#define F_DIM 128
#define NG 3
#define XCDS 8
#define EPT 8        // edges per thread in build
#define CAP 48       // fixed per-node CSR capacity (mean deg 16, max ~35)
#define SPILL_CAP 8192

typedef __attribute__((ext_vector_type(8))) short short8_t;
typedef __attribute__((ext_vector_type(4))) float f32x4;

__device__ __forceinline__ unsigned short f2bf(float f) {
    unsigned int x = __float_as_uint(f);
    unsigned int r = x + 0x7fffu + ((x >> 16) & 1u);  // RNE
    return (unsigned short)(r >> 16);
}
__device__ __forceinline__ float bflo(unsigned int u) { return __uint_as_float(u << 16); }
__device__ __forceinline__ float bfhi(unsigned int u) { return __uint_as_float(u & 0xffff0000u); }

struct GArgs {
    const int* src[NG]; const int* dst[NG];
    const float* X[NG]; const float* W[NG]; const float* b[NG];
    float* out[NG];
    unsigned short* Xps[NG];  // bf16 row-major [N][128], pre-scaled by dinv[row]
    int* cursor[NG];          // [N] bucket cursors (init i*CAP)
    int* cstore[NG];          // [N] stored counts (<=CAP)
    float* dinv[NG];          // [N]
    int* sorted[NG];          // [N*CAP]
    int* spill[NG];           // [SPILL_CAP*2] (src,dst) pairs
    int* spill_n[NG];         // [1]
};

// ---- init: cursor[i] = i*CAP; spill_n = 0 ------------------------------------
__global__ __launch_bounds__(256) void init_kernel(GArgs a, int g0, int n) {
    int g = g0 + blockIdx.y;
    int i = blockIdx.x * 256 + threadIdx.x;
    if (i < n) a.cursor[g][i] = i * CAP;
    if (i == 0) a.spill_n[g][0] = 0;
}

// ---- bucket-scatter, XCD-partitioned by dst-range. Also produces degrees. ----
// NT loads on the streamed edge arrays keep sorted/cursor L2-resident.
__global__ __launch_bounds__(256) void build_kernel(GArgs a, int g0, int E, int nPerX) {
    int g = g0 + blockIdx.y;
    int xcd = blockIdx.x % XCDS;
    int lo = xcd * nPerX, hi = lo + nPerX;
    const int* dst = a.dst[g];
    const int* src = a.src[g];
    int* cursor = a.cursor[g];
    int* sorted = a.sorted[g];
    int base = (blockIdx.x / XCDS) * (256 * EPT) + threadIdx.x;
#pragma unroll
    for (int i = 0; i < EPT; ++i) {
        int e = base + i * 256;
        if (e < E) {
            int d = __builtin_nontemporal_load(&dst[e]);
            if (d >= lo && d < hi) {
                int sv = __builtin_nontemporal_load(&src[e]);
                int p = atomicAdd(&cursor[d], 1);
                if (p < d * CAP + CAP) {
                    sorted[p] = sv;
                } else {
                    int sp = atomicAdd(a.spill_n[g], 1);
                    if (sp < SPILL_CAP) {
                        a.spill[g][2 * sp] = sv;
                        a.spill[g][2 * sp + 1] = d;
                    }
                }
            }
        }
    }
}

// ---- counts + dinv from cursors ----------------------------------------------
__global__ __launch_bounds__(256) void counts_kernel(GArgs a, int g0, int n) {
    int g = g0 + blockIdx.y;
    int i = blockIdx.x * 256 + threadIdx.x;
    if (i >= n) return;
    int deg = a.cursor[g][i] - i * CAP;
    a.cstore[g][i] = min(deg, CAP);
    a.dinv[g][i] = rsqrtf((float)deg + 1.0f);
}

// ---- MFMA bf16 GEMM: Xps(bf16 row-major) = dinv[row] * (X @ W + b) -----------
__global__ __launch_bounds__(256) void gemm_kernel(GArgs a, int g0, int n) {
    int g = g0 + blockIdx.y;
    __shared__ unsigned short Xl[128 * 128];
    __shared__ unsigned short Wt[128 * 128];
    const int t = threadIdx.x;
    const int row0 = blockIdx.x * 128;
    const float* X = a.X[g];
    const float* W = a.W[g];
    char* XlB = (char*)Xl;
    char* WtB = (char*)Wt;

    for (int i = t; i < 128 * 16; i += 256) {
        int r = i >> 4, kc = i & 15;
        int row = row0 + r;
        float4 x0 = make_float4(0.f, 0.f, 0.f, 0.f), x1 = x0;
        if (row < n) {
            const float4* xp = (const float4*)(X + (size_t)row * F_DIM + kc * 8);
            x0 = xp[0]; x1 = xp[1];
        }
        uint4 pk;
        pk.x = (unsigned)f2bf(x0.x) | ((unsigned)f2bf(x0.y) << 16);
        pk.y = (unsigned)f2bf(x0.z) | ((unsigned)f2bf(x0.w) << 16);
        pk.z = (unsigned)f2bf(x1.x) | ((unsigned)f2bf(x1.y) << 16);
        pk.w = (unsigned)f2bf(x1.z) | ((unsigned)f2bf(x1.w) << 16);
        unsigned int ad = (unsigned)((r << 8) + (kc << 4)) ^ (unsigned)((r & 15) << 4);
        *(uint4*)(XlB + ad) = pk;
    }
    for (int i = t; i < 128 * 16; i += 256) {
        int nn = i & 127, kc = i >> 7;
        const float* wp = W + (size_t)(kc * 8) * F_DIM + nn;
        uint4 pk;
        pk.x = (unsigned)f2bf(wp[0])   | ((unsigned)f2bf(wp[128]) << 16);
        pk.y = (unsigned)f2bf(wp[256]) | ((unsigned)f2bf(wp[384]) << 16);
        pk.z = (unsigned)f2bf(wp[512]) | ((unsigned)f2bf(wp[640]) << 16);
        pk.w = (unsigned)f2bf(wp[768]) | ((unsigned)f2bf(wp[896]) << 16);
        unsigned int ad = (unsigned)((nn << 8) + (kc << 4)) ^ (unsigned)((nn & 15) << 4);
        *(uint4*)(WtB + ad) = pk;
    }
    __syncthreads();

    const int l = t & 63;
    const int wv = t >> 6;
    const int wr = wv >> 1, wc = wv & 1;
    const int lm = l & 15;
    const int lk = l >> 4;

    f32x4 acc[4][4] = {};
#pragma unroll
    for (int ks = 0; ks < 4; ++ks) {
        const int kb = ks * 64 + lk * 16;
        short8_t af[4], bv[4];
#pragma unroll
        for (int mt = 0; mt < 4; ++mt) {
            int r = wr * 64 + mt * 16 + lm;
            unsigned int ad = (unsigned)((r << 8) + kb) ^ (unsigned)((r & 15) << 4);
            af[mt] = *(const short8_t*)(XlB + ad);
        }
#pragma unroll
        for (int nt = 0; nt < 4; ++nt) {
            int c = wc * 64 + nt * 16 + lm;
            unsigned int ad = (unsigned)((c << 8) + kb) ^ (unsigned)((c & 15) << 4);
            bv[nt] = *(const short8_t*)(WtB + ad);
        }
#pragma unroll
        for (int mt = 0; mt < 4; ++mt)
#pragma unroll
            for (int nt = 0; nt < 4; ++nt)
                acc[mt][nt] = __builtin_amdgcn_mfma_f32_16x16x32_bf16(af[mt], bv[nt],
                                                                      acc[mt][nt], 0, 0, 0);
    }

    const float* bia = a.b[g];
    const float* dinv = a.dinv[g];
    unsigned short* Xps = a.Xps[g];
#pragma unroll
    for (int nt = 0; nt < 4; ++nt) {
        int col = wc * 64 + nt * 16 + lm;
        float bc = bia[col];
#pragma unroll
        for (int mt = 0; mt < 4; ++mt) {
            int rbase = row0 + wr * 64 + mt * 16 + lk * 4;
#pragma unroll
            for (int r = 0; r < 4; ++r) {
                int row = rbase + r;
                if (row < n) {
                    float v = (acc[mt][nt][r] + bc) * dinv[row];
                    Xps[(size_t)row * F_DIM + col] = f2bf(v);
                }
            }
        }
    }
}

// ---- aggregation: one wave per node; 8-deep batched gathers (MLP=8) ----------
__global__ __launch_bounds__(256) void agg_kernel(GArgs a, int g0, int n) {
    int g = g0 + blockIdx.y;
    int wave = (blockIdx.x * 256 + threadIdx.x) >> 6;
    if (wave >= n) return;
    int lane = threadIdx.x & 63;
    const unsigned int* Xp = (const unsigned int*)a.Xps[g];  // 64 u32 per row
    const int* sorted = a.sorted[g];
    int beg = wave * CAP;
    int cnt = a.cstore[g][wave];
    unsigned int u0 = Xp[(size_t)wave * 64 + lane];
    float ax = bflo(u0), ay = bfhi(u0);
    for (int j = 0; j < cnt;) {
        int m = min(cnt - j, 64);
        int s = (j + lane < cnt) ? __builtin_nontemporal_load(&sorted[beg + j + lane]) : 0;
        int k = 0;
        for (; k + 8 <= m; k += 8) {
            int s0 = __shfl(s, k + 0, 64), s1 = __shfl(s, k + 1, 64);
            int s2 = __shfl(s, k + 2, 64), s3 = __shfl(s, k + 3, 64);
            int s4 = __shfl(s, k + 4, 64), s5 = __shfl(s, k + 5, 64);
            int s6 = __shfl(s, k + 6, 64), s7 = __shfl(s, k + 7, 64);
            unsigned int v0 = Xp[(size_t)s0 * 64 + lane];
            unsigned int v1 = Xp[(size_t)s1 * 64 + lane];
            unsigned int v2 = Xp[(size_t)s2 * 64 + lane];
            unsigned int v3 = Xp[(size_t)s3 * 64 + lane];
            unsigned int v4 = Xp[(size_t)s4 * 64 + lane];
            unsigned int v5 = Xp[(size_t)s5 * 64 + lane];
            unsigned int v6 = Xp[(size_t)s6 * 64 + lane];
            unsigned int v7 = Xp[(size_t)s7 * 64 + lane];
            ax += bflo(v0); ay += bfhi(v0);
            ax += bflo(v1); ay += bfhi(v1);
            ax += bflo(v2); ay += bfhi(v2);
            ax += bflo(v3); ay += bfhi(v3);
            ax += bflo(v4); ay += bfhi(v4);
            ax += bflo(v5); ay += bfhi(v5);
            ax += bflo(v6); ay += bfhi(v6);
            ax += bflo(v7); ay += bfhi(v7);
        }
        if (k + 4 <= m) {
            int s0 = __shfl(s, k + 0, 64), s1 = __shfl(s, k + 1, 64);
            int s2 = __shfl(s, k + 2, 64), s3 = __shfl(s, k + 3, 64);
            unsigned int v0 = Xp[(size_t)s0 * 64 + lane];
            unsigned int v1 = Xp[(size_t)s1 * 64 + lane];
            unsigned int v2 = Xp[(size_t)s2 * 64 + lane];
            unsigned int v3 = Xp[(size_t)s3 * 64 + lane];
            ax += bflo(v0); ay += bfhi(v0);
            ax += bflo(v1); ay += bfhi(v1);
            ax += bflo(v2); ay += bfhi(v2);
            ax += bflo(v3); ay += bfhi(v3);
            k += 4;
        }
        for (; k < m; ++k) {
            int sk = __shfl(s, k, 64);
            unsigned int v = Xp[(size_t)sk * 64 + lane];
            ax += bflo(v);
            ay += bfhi(v);
        }
        j += m;
    }
    float dd = a.dinv[g][wave];
    ((float2*)a.out[g])[(size_t)wave * 64 + lane] = make_float2(ax * dd, ay * dd);
}

// ---- spill cleanup: out[d] += dinv[d] * Xps[s] for overflow edges ------------
__global__ __launch_bounds__(128) void spill_kernel(GArgs a, int g0) {
    int g = g0 + blockIdx.y;
    int ns = min(a.spill_n[g][0], SPILL_CAP);
    const unsigned short* Xps = a.Xps[g];
    const float* dinv = a.dinv[g];
    float* out = a.out[g];
    for (int i = blockIdx.x; i < ns; i += gridDim.x) {
        int s = a.spill[g][2 * i];
        int d = a.spill[g][2 * i + 1];
        float w = dinv[d];
        int f = threadIdx.x;
        float v = __uint_as_float(((unsigned int)Xps[(size_t)s * F_DIM + f]) << 16);
        unsafeAtomicAdd(&out[(size_t)d * F_DIM + f], w * v);
    }
}

extern "C" void kernel_launch(void* const* d_in, const int* in_sizes, int n_in,
                              void* d_out, int out_size, void* d_ws, size_t ws_size,
                              hipStream_t stream) {
    const float* Xin[NG] = {(const float*)d_in[0], (const float*)d_in[1], (const float*)d_in[2]};
    const int* ei[NG] = {(const int*)d_in[3], (const int*)d_in[4], (const int*)d_in[5]};
    const float* Wk[NG] = {(const float*)d_in[6], (const float*)d_in[8], (const float*)d_in[10]};
    const float* bk[NG] = {(const float*)d_in[7], (const float*)d_in[9], (const float*)d_in[11]};

    const int N = in_sizes[0] / F_DIM;  // 50000
    const int E = in_sizes[3] / 2;      // 800000
    float* out = (float*)d_out;

    const size_t xps_b = (size_t)N * F_DIM * 2;       // bf16
    const size_t sorted_b = (size_t)N * CAP * 4;
    const size_t nb = (size_t)N * 4;
    const size_t spill_b = (size_t)SPILL_CAP * 8 + 64;
    const size_t per = ((xps_b + sorted_b + 3 * nb + spill_b + 255) / 256) * 256;
    const bool fused = ws_size >= (size_t)NG * per;
    char* base = (char*)d_ws;

    GArgs a;
    for (int r = 0; r < NG; ++r) {
        char* s = base + (size_t)(fused ? r : 0) * per;
        a.Xps[r] = (unsigned short*)s;
        a.sorted[r] = (int*)(s + xps_b);
        a.cursor[r] = (int*)(s + xps_b + sorted_b);
        a.cstore[r] = (int*)(s + xps_b + sorted_b + nb);
        a.dinv[r] = (float*)(s + xps_b + sorted_b + 2 * nb);
        a.spill[r] = (int*)(s + xps_b + sorted_b + 3 * nb);
        a.spill_n[r] = (int*)(s + xps_b + sorted_b + 3 * nb + spill_b - 64);
        a.src[r] = ei[r];
        a.dst[r] = ei[r] + E;
        a.X[r] = Xin[r];
        a.W[r] = Wk[r];
        a.b[r] = bk[r];
        a.out[r] = out + (size_t)r * N * F_DIM;
    }

    const dim3 blk(256);
    const int nPerX = (N + XCDS - 1) / XCDS;
    const int chunks = (E + 256 * EPT - 1) / (256 * EPT);
    const int gP = chunks * XCDS;
    const int gN = (N + 255) / 256;
    const int gR = (N + 127) / 128;
    const int gA = (N * 64 + 255) / 256;

    if (fused) {
        init_kernel<<<dim3(gN, NG), blk, 0, stream>>>(a, 0, N);
        build_kernel<<<dim3(gP, NG), blk, 0, stream>>>(a, 0, E, nPerX);
        counts_kernel<<<dim3(gN, NG), blk, 0, stream>>>(a, 0, N);
        gemm_kernel<<<dim3(gR, NG), blk, 0, stream>>>(a, 0, N);
        agg_kernel<<<dim3(gA, NG), blk, 0, stream>>>(a, 0, N);
        spill_kernel<<<dim3(16, NG), dim3(128), 0, stream>>>(a, 0);
    } else {
        for (int g = 0; g < NG; ++g) {
            init_kernel<<<dim3(gN, 1), blk, 0, stream>>>(a, g, N);
            build_kernel<<<dim3(gP, 1), blk, 0, stream>>>(a, g, E, nPerX);
            counts_kernel<<<dim3(gN, 1), blk, 0, stream>>>(a, g, N);
            gemm_kernel<<<dim3(gR, 1), blk, 0, stream>>>(a, g, N);
            agg_kernel<<<dim3(gA, 1), blk, 0, stream>>>(a, g, N);
            spill_kernel<<<dim3(16, 1), dim3(128), 0, stream>>>(a, g);
        }
    }
}